// Round 10
// baseline (200.963 us; speedup 1.0000x reference)
//
#include <hip/hip_runtime.h>

// ============================================================================
// WignerKernelReducedCost: per-b CG tensor-product tower.
//   out[b,0] = x0[b]
//   Y = combine(X, X, 3)           (7 keys: 0_1, 1_±1, 2_±1, 3_±1)
//   out[b,1] = Y['0_1']
//   out[b,2] = combine(Y, X, 0)['0_1'] = sum_l inv(2l+1) signed dot(Y[l_1], X_l)
//   out[b,3] = combine(Y, Y, 0)['0_1'] = sum_{l,s} inv(2l+1) selfdot(Y[l_s])
//
// Round-10 = R9 (pair-streaming + opaque fences + dual chains; 51.7us,
// 128 VGPR, spills ELIMINATED: WRITE 4.7MB ~= output-ideal, VALUBusy 66%)
// with the occupancy mechanism changed: waves_per_eu(2,2) -> launch_bounds
// (256, 4). Live set ~95 floats fits the 128-VGPR / 4-waves-per-EU tier, so
// min-4-waves doubles latency hiding (fma chains + I-fetch on the ~100KB
// straight-line body) at the same register tier R9 already used.
// R6/R8 lesson distinguished: (4,4)/(3,3) under-allocated (64/84 VGPR) and
// spilled because the THEN-live-set (140, materialized Y) exceeded budget;
// pair-streaming removed that pressure.
// Opaque-fence lesson (R1-R3): IR-level GVN/CSE hoists cross-key temporaries
// past any scheduler fence; only asm volatile("" : "+v") value fences stop it.
// All CG coefficients fold to immediates at compile time.
// ============================================================================

#define SCHED_FENCE() __builtin_amdgcn_sched_barrier(0)

template <int N>
__device__ __forceinline__ void opaque(float (&A)[N]) {
#pragma unroll
  for (int i = 0; i < N; ++i) asm volatile("" : "+v"(A[i]));
}
__device__ __forceinline__ void opaque1(float& x) { asm volatile("" : "+v"(x)); }

// ---------- compile-time Clebsch-Gordan (Racah formula) ----------
constexpr double cfact(int n) { double r = 1.0; for (int i = 2; i <= n; ++i) r *= (double)i; return r; }

constexpr double csqrt(double x) {
  if (x <= 0.0) return 0.0;
  double g = x > 1.0 ? x : 1.0;
  for (int i = 0; i < 100; ++i) g = 0.5 * (g + x / g);
  return g;
}

constexpr double cg_val(int l1, int l2, int L, int m1, int m2) {
  const int M = m1 + m2;
  if (M < -L || M > L) return 0.0;
  const double pref0 = csqrt((2.0 * L + 1.0) * cfact(L + l1 - l2) * cfact(L - l1 + l2) *
                             cfact(l1 + l2 - L) / cfact(l1 + l2 + L + 1));
  const double pref = pref0 * csqrt(cfact(L + M) * cfact(L - M) * cfact(l1 - m1) *
                                    cfact(l1 + m1) * cfact(l2 - m2) * cfact(l2 + m2));
  double s = 0.0;
  for (int k = 0; k <= l1 + l2 - L; ++k) {
    if (l1 - m1 - k < 0 || l2 + m2 - k < 0 || L - l2 + m1 + k < 0 || L - l1 - m2 + k < 0) continue;
    const double t = 1.0 / (cfact(k) * cfact(l1 + l2 - L - k) * cfact(l1 - m1 - k) *
                            cfact(l2 + m2 - k) * cfact(L - l2 + m1 + k) * cfact(L - l1 - m2 + k));
    s += (k & 1) ? -t : t;
  }
  return pref * s;
}

// Table a[mi][kk] = <l1 (mi-l1); l2 (kk-L-(mi-l1)) | L (kk-L)>  (0 if m2 out of range)
template <int l1, int l2, int L>
struct CG2T {
  double a[2 * l1 + 1][2 * L + 1];
  constexpr CG2T() : a{} {
    for (int mi = 0; mi < 2 * l1 + 1; ++mi)
      for (int kk = 0; kk < 2 * L + 1; ++kk) {
        const int m1 = mi - l1, M = kk - L, m2 = M - m1;
        a[mi][kk] = (m2 < -l2 || m2 > l2) ? 0.0 : cg_val(l1, l2, L, m1, m2);
      }
  }
};
template <int l1, int l2, int L>
constexpr CG2T<l1, l2, L> CG2v = CG2T<l1, l2, L>();

// ---------- contribution of one (l1,l2,L) triple to ONE Y element ----------
// W=2 encodes the (l1,l2)/(l2,l1) pair symmetry (contributions identical).
// For l1==l2 (K1==K2), terms (m,p) and (n,q) within the SAME element have
// identical coefficient and product -> keep id1<=id2 with factor 2.
// Dual parity-interleaved accumulator chains (compile-time after unroll).
template <int l1, int l2, int L, int W>
__device__ __forceinline__ float triElem(const float (&K1)[(2 * l1 + 1) * (2 * l1 + 1)],
                                         const float (&K2)[(2 * l2 + 1) * (2 * l2 + 1)],
                                         int kk, int jj) {
  constexpr int d1 = 2 * l1 + 1, d2 = 2 * l2 + 1;
  float a0 = 0.f, a1 = 0.f;
#pragma unroll
  for (int mi = 0; mi < d1; ++mi) {
    const int ni = (kk - L) - (mi - l1) + l2;  // m2 index in K2
    if (ni < 0 || ni >= d2) continue;
#pragma unroll
    for (int pi = 0; pi < d1; ++pi) {
      const int qi = (jj - L) - (pi - l1) + l2;
      if (qi < 0 || qi >= d2) continue;
      const double c0 = CG2v<l1, l2, L>.a[mi][kk] * CG2v<l1, l2, L>.a[pi][jj];
      if (c0 == 0.0) continue;  // folded at compile time
      double c = c0 * (double)W;
      if constexpr (l1 == l2) {
        const int id1 = mi * d1 + pi, id2 = ni * d1 + qi;
        if (id1 > id2) continue;   // partner term covers it
        if (id1 < id2) c *= 2.0;   // merged pair
      }
      if ((mi + pi) & 1)
        a1 = fmaf((float)c * K1[mi * d1 + pi], K2[ni * d2 + qi], a1);
      else
        a0 = fmaf((float)c * K1[mi * d1 + pi], K2[ni * d2 + qi], a0);
    }
  }
  return a0 + a1;
}

// ---------- stream one key: pairs {(i,j),(2l-i,2l-j)} -> o3/o4, no Y array ----------
// Each Y element is computed exactly once (pairs partition the d*d grid).
// o4 += inv(2l+1) * sum (-1)^(i+j) Y[i,j] Y[2l-i,2l-j]
// o3 += inv(2l+1) * sum (-1)^(i+j) Y[i,j] X[2l-i,2l-j]   (sig=+1 keys only)
template <int l, bool HAS_O3, typename F>
__device__ __forceinline__ void reduceKey(F yel, const float (&Xl)[(2 * l + 1) * (2 * l + 1)],
                                          float& o3, float& o4) {
  constexpr int d = 2 * l + 1;
  constexpr float inv = 1.0f / (float)d;
#pragma unroll
  for (int i = 0; i < d; ++i) {
#pragma unroll
    for (int j = 0; j < d; ++j) {
      const int id = i * d + j, id2 = d * d - 1 - id;  // (2l-i, 2l-j)
      if (id > id2) continue;
      const float c = (((i + j) & 1) ? -inv : inv);
      const float y1 = yel(i, j);
      if (id == id2) {  // center element
        o4 = fmaf(c * y1, y1, o4);
        if constexpr (HAS_O3) o3 = fmaf(c * y1, Xl[id2], o3);
      } else {
        const float y2 = yel(2 * l - i, 2 * l - j);
        o4 = fmaf((2.0f * c) * y1, y2, o4);
        if constexpr (HAS_O3) {
          o3 = fmaf(c * y1, Xl[id2], o3);
          o3 = fmaf(c * y2, Xl[id], o3);
        }
      }
    }
  }
}

__global__ __launch_bounds__(256, 4) void wigner_kernel(
    const float* __restrict__ x0, const float* __restrict__ x1,
    const float* __restrict__ x2, const float* __restrict__ x3,
    float* __restrict__ out, int n) {
  const int b = blockIdx.x * blockDim.x + threadIdx.x;
  if (b >= n) return;

  float X0[1], X1[9], X2[25], X3[49];
  X0[0] = x0[b];
#pragma unroll
  for (int i = 0; i < 9; ++i) X1[i] = x1[b * 9 + i];
#pragma unroll
  for (int i = 0; i < 25; ++i) X2[i] = x2[b * 25 + i];
#pragma unroll
  for (int i = 0; i < 49; ++i) X3[i] = x3[b * 49 + i];

  float o2, o3 = 0.f, o4 = 0.f;

  // full value fence: X becomes "new" values; nothing computed from old X
  // can be reused past this point; also pins schedule.
#define KEY_FENCE()                                                   \
  do {                                                                \
    opaque(X0); opaque(X1); opaque(X2); opaque(X3);                   \
    opaque1(o3); opaque1(o4);                                         \
    SCHED_FENCE();                                                    \
  } while (0)

  KEY_FENCE();

  {  // key 0_1 : (0,0) (1,1) (2,2) (3,3)  — scalar, inline
    float y = triElem<0, 0, 0, 1>(X0, X0, 0, 0)
            + triElem<1, 1, 0, 1>(X1, X1, 0, 0)
            + triElem<2, 2, 0, 1>(X2, X2, 0, 0)
            + triElem<3, 3, 0, 1>(X3, X3, 0, 0);
    o2 = y;
    o3 = fmaf(y, X0[0], o3);
    o4 = fmaf(y, y, o4);
  }
  KEY_FENCE();
  {  // key 1_1 : (0,1)x2 (1,2)x2 (2,3)x2
    auto yel = [&](int i, int j) {
      return triElem<0, 1, 1, 2>(X0, X1, i, j)
           + triElem<1, 2, 1, 2>(X1, X2, i, j)
           + triElem<2, 3, 1, 2>(X2, X3, i, j);
    };
    reduceKey<1, true>(yel, X1, o3, o4);
  }
  KEY_FENCE();
  {  // key 1_-1 : (1,1) (2,2) (3,3)
    auto yel = [&](int i, int j) {
      return triElem<1, 1, 1, 1>(X1, X1, i, j)
           + triElem<2, 2, 1, 1>(X2, X2, i, j)
           + triElem<3, 3, 1, 1>(X3, X3, i, j);
    };
    reduceKey<1, false>(yel, X1, o3, o4);
  }
  KEY_FENCE();
  {  // key 2_1 : (0,2)x2 (1,1) (1,3)x2 (2,2) (3,3)
    auto yel = [&](int i, int j) {
      return triElem<0, 2, 2, 2>(X0, X2, i, j)
           + triElem<1, 1, 2, 1>(X1, X1, i, j)
           + triElem<1, 3, 2, 2>(X1, X3, i, j)
           + triElem<2, 2, 2, 1>(X2, X2, i, j)
           + triElem<3, 3, 2, 1>(X3, X3, i, j);
    };
    reduceKey<2, true>(yel, X2, o3, o4);
  }
  KEY_FENCE();
  {  // key 2_-1 : (1,2)x2 (2,3)x2
    auto yel = [&](int i, int j) {
      return triElem<1, 2, 2, 2>(X1, X2, i, j)
           + triElem<2, 3, 2, 2>(X2, X3, i, j);
    };
    reduceKey<2, false>(yel, X2, o3, o4);
  }
  KEY_FENCE();
  {  // key 3_1 : (0,3)x2 (1,2)x2 (2,3)x2
    auto yel = [&](int i, int j) {
      return triElem<0, 3, 3, 2>(X0, X3, i, j)
           + triElem<1, 2, 3, 2>(X1, X2, i, j)
           + triElem<2, 3, 3, 2>(X2, X3, i, j);
    };
    reduceKey<3, true>(yel, X3, o3, o4);
  }
  KEY_FENCE();
  {  // key 3_-1 : (1,3)x2 (2,2) (3,3)
    auto yel = [&](int i, int j) {
      return triElem<1, 3, 3, 2>(X1, X3, i, j)
           + triElem<2, 2, 3, 1>(X2, X2, i, j)
           + triElem<3, 3, 3, 1>(X3, X3, i, j);
    };
    reduceKey<3, false>(yel, X3, o3, o4);
  }
#undef KEY_FENCE

  reinterpret_cast<float4*>(out)[b] = make_float4(X0[0], o2, o3, o4);
}

extern "C" void kernel_launch(void* const* d_in, const int* in_sizes, int n_in,
                              void* d_out, int out_size, void* d_ws, size_t ws_size,
                              hipStream_t stream) {
  const float* x0 = (const float*)d_in[0];
  const float* x1 = (const float*)d_in[1];
  const float* x2 = (const float*)d_in[2];
  const float* x3 = (const float*)d_in[3];
  float* out = (float*)d_out;
  const int n = in_sizes[0];  // B (x0 has 1 element per b)
  const int block = 256;
  const int grid = (n + block - 1) / block;
  wigner_kernel<<<grid, block, 0, stream>>>(x0, x1, x2, x3, out, n);
}

// Round 11
// 125.989 us; speedup vs baseline: 1.5951x; 1.5951x over previous
//
#include <hip/hip_runtime.h>

// ============================================================================
// WignerKernelReducedCost: per-b CG tensor-product tower.
//   out[b,0] = x0[b]
//   Y = combine(X, X, 3)           (7 keys: 0_1, 1_±1, 2_±1, 3_±1)
//   out[b,1] = Y['0_1']
//   out[b,2] = combine(Y, X, 0)['0_1'] = sum_l inv(2l+1) signed dot(Y[l_1], X_l)
//   out[b,3] = combine(Y, Y, 0)['0_1'] = sum_{l,s} inv(2l+1) selfdot(Y[l_s])
//
// Round-11 = R9 (pair-streaming + opaque fences + dual chains; BEST: 51.7us,
// 128 VGPR, no spill (WRITE 4.7MB), VALUBusy 66%, Occupancy 14.5%) with ONE
// change: amdgpu_waves_per_eu(2,2) -> (2,4).
//   min=2 keeps the allocator budget that produced the proven spill-free
//   128-VGPR binary; max=4 permits 4 resident waves/EU (128 VGPR allows it).
//   R9's 34% VALU-idle tracks its ~1.2 waves/SIMD residency: one wave of
//   4-cyc fmaf chains at 2-cyc issue can't fill the pipe; 4 waves can.
// Occupancy-attr lesson (R6/R8/R10): ANY min-occupancy >=3 (waves_per_eu
// (3,3)/(4,4), launch_bounds(256,4)) makes the backend budget for ~2x that
// occupancy (84/64/64 VGPR) and spill massively. min=2 is the only safe
// setting; only the MAX may be raised.
// Opaque-fence lesson (R1-R3): IR-level GVN/CSE hoists cross-key temporaries
// past any scheduler fence; only asm volatile("" : "+v") value fences stop it.
// All CG coefficients fold to immediates at compile time.
// ============================================================================

#define SCHED_FENCE() __builtin_amdgcn_sched_barrier(0)

template <int N>
__device__ __forceinline__ void opaque(float (&A)[N]) {
#pragma unroll
  for (int i = 0; i < N; ++i) asm volatile("" : "+v"(A[i]));
}
__device__ __forceinline__ void opaque1(float& x) { asm volatile("" : "+v"(x)); }

// ---------- compile-time Clebsch-Gordan (Racah formula) ----------
constexpr double cfact(int n) { double r = 1.0; for (int i = 2; i <= n; ++i) r *= (double)i; return r; }

constexpr double csqrt(double x) {
  if (x <= 0.0) return 0.0;
  double g = x > 1.0 ? x : 1.0;
  for (int i = 0; i < 100; ++i) g = 0.5 * (g + x / g);
  return g;
}

constexpr double cg_val(int l1, int l2, int L, int m1, int m2) {
  const int M = m1 + m2;
  if (M < -L || M > L) return 0.0;
  const double pref0 = csqrt((2.0 * L + 1.0) * cfact(L + l1 - l2) * cfact(L - l1 + l2) *
                             cfact(l1 + l2 - L) / cfact(l1 + l2 + L + 1));
  const double pref = pref0 * csqrt(cfact(L + M) * cfact(L - M) * cfact(l1 - m1) *
                                    cfact(l1 + m1) * cfact(l2 - m2) * cfact(l2 + m2));
  double s = 0.0;
  for (int k = 0; k <= l1 + l2 - L; ++k) {
    if (l1 - m1 - k < 0 || l2 + m2 - k < 0 || L - l2 + m1 + k < 0 || L - l1 - m2 + k < 0) continue;
    const double t = 1.0 / (cfact(k) * cfact(l1 + l2 - L - k) * cfact(l1 - m1 - k) *
                            cfact(l2 + m2 - k) * cfact(L - l2 + m1 + k) * cfact(L - l1 - m2 + k));
    s += (k & 1) ? -t : t;
  }
  return pref * s;
}

// Table a[mi][kk] = <l1 (mi-l1); l2 (kk-L-(mi-l1)) | L (kk-L)>  (0 if m2 out of range)
template <int l1, int l2, int L>
struct CG2T {
  double a[2 * l1 + 1][2 * L + 1];
  constexpr CG2T() : a{} {
    for (int mi = 0; mi < 2 * l1 + 1; ++mi)
      for (int kk = 0; kk < 2 * L + 1; ++kk) {
        const int m1 = mi - l1, M = kk - L, m2 = M - m1;
        a[mi][kk] = (m2 < -l2 || m2 > l2) ? 0.0 : cg_val(l1, l2, L, m1, m2);
      }
  }
};
template <int l1, int l2, int L>
constexpr CG2T<l1, l2, L> CG2v = CG2T<l1, l2, L>();

// ---------- contribution of one (l1,l2,L) triple to ONE Y element ----------
// W=2 encodes the (l1,l2)/(l2,l1) pair symmetry (contributions identical).
// For l1==l2 (K1==K2), terms (m,p) and (n,q) within the SAME element have
// identical coefficient and product -> keep id1<=id2 with factor 2.
// Dual parity-interleaved accumulator chains (compile-time after unroll).
template <int l1, int l2, int L, int W>
__device__ __forceinline__ float triElem(const float (&K1)[(2 * l1 + 1) * (2 * l1 + 1)],
                                         const float (&K2)[(2 * l2 + 1) * (2 * l2 + 1)],
                                         int kk, int jj) {
  constexpr int d1 = 2 * l1 + 1, d2 = 2 * l2 + 1;
  float a0 = 0.f, a1 = 0.f;
#pragma unroll
  for (int mi = 0; mi < d1; ++mi) {
    const int ni = (kk - L) - (mi - l1) + l2;  // m2 index in K2
    if (ni < 0 || ni >= d2) continue;
#pragma unroll
    for (int pi = 0; pi < d1; ++pi) {
      const int qi = (jj - L) - (pi - l1) + l2;
      if (qi < 0 || qi >= d2) continue;
      const double c0 = CG2v<l1, l2, L>.a[mi][kk] * CG2v<l1, l2, L>.a[pi][jj];
      if (c0 == 0.0) continue;  // folded at compile time
      double c = c0 * (double)W;
      if constexpr (l1 == l2) {
        const int id1 = mi * d1 + pi, id2 = ni * d1 + qi;
        if (id1 > id2) continue;   // partner term covers it
        if (id1 < id2) c *= 2.0;   // merged pair
      }
      if ((mi + pi) & 1)
        a1 = fmaf((float)c * K1[mi * d1 + pi], K2[ni * d2 + qi], a1);
      else
        a0 = fmaf((float)c * K1[mi * d1 + pi], K2[ni * d2 + qi], a0);
    }
  }
  return a0 + a1;
}

// ---------- stream one key: pairs {(i,j),(2l-i,2l-j)} -> o3/o4, no Y array ----------
// Each Y element is computed exactly once (pairs partition the d*d grid).
// o4 += inv(2l+1) * sum (-1)^(i+j) Y[i,j] Y[2l-i,2l-j]
// o3 += inv(2l+1) * sum (-1)^(i+j) Y[i,j] X[2l-i,2l-j]   (sig=+1 keys only)
template <int l, bool HAS_O3, typename F>
__device__ __forceinline__ void reduceKey(F yel, const float (&Xl)[(2 * l + 1) * (2 * l + 1)],
                                          float& o3, float& o4) {
  constexpr int d = 2 * l + 1;
  constexpr float inv = 1.0f / (float)d;
#pragma unroll
  for (int i = 0; i < d; ++i) {
#pragma unroll
    for (int j = 0; j < d; ++j) {
      const int id = i * d + j, id2 = d * d - 1 - id;  // (2l-i, 2l-j)
      if (id > id2) continue;
      const float c = (((i + j) & 1) ? -inv : inv);
      const float y1 = yel(i, j);
      if (id == id2) {  // center element
        o4 = fmaf(c * y1, y1, o4);
        if constexpr (HAS_O3) o3 = fmaf(c * y1, Xl[id2], o3);
      } else {
        const float y2 = yel(2 * l - i, 2 * l - j);
        o4 = fmaf((2.0f * c) * y1, y2, o4);
        if constexpr (HAS_O3) {
          o3 = fmaf(c * y1, Xl[id2], o3);
          o3 = fmaf(c * y2, Xl[id], o3);
        }
      }
    }
  }
}

__global__ __launch_bounds__(256)
__attribute__((amdgpu_waves_per_eu(2, 4)))
void wigner_kernel(
    const float* __restrict__ x0, const float* __restrict__ x1,
    const float* __restrict__ x2, const float* __restrict__ x3,
    float* __restrict__ out, int n) {
  const int b = blockIdx.x * blockDim.x + threadIdx.x;
  if (b >= n) return;

  float X0[1], X1[9], X2[25], X3[49];
  X0[0] = x0[b];
#pragma unroll
  for (int i = 0; i < 9; ++i) X1[i] = x1[b * 9 + i];
#pragma unroll
  for (int i = 0; i < 25; ++i) X2[i] = x2[b * 25 + i];
#pragma unroll
  for (int i = 0; i < 49; ++i) X3[i] = x3[b * 49 + i];

  float o2, o3 = 0.f, o4 = 0.f;

  // full value fence: X becomes "new" values; nothing computed from old X
  // can be reused past this point; also pins schedule.
#define KEY_FENCE()                                                   \
  do {                                                                \
    opaque(X0); opaque(X1); opaque(X2); opaque(X3);                   \
    opaque1(o3); opaque1(o4);                                         \
    SCHED_FENCE();                                                    \
  } while (0)

  KEY_FENCE();

  {  // key 0_1 : (0,0) (1,1) (2,2) (3,3)  — scalar, inline
    float y = triElem<0, 0, 0, 1>(X0, X0, 0, 0)
            + triElem<1, 1, 0, 1>(X1, X1, 0, 0)
            + triElem<2, 2, 0, 1>(X2, X2, 0, 0)
            + triElem<3, 3, 0, 1>(X3, X3, 0, 0);
    o2 = y;
    o3 = fmaf(y, X0[0], o3);
    o4 = fmaf(y, y, o4);
  }
  KEY_FENCE();
  {  // key 1_1 : (0,1)x2 (1,2)x2 (2,3)x2
    auto yel = [&](int i, int j) {
      return triElem<0, 1, 1, 2>(X0, X1, i, j)
           + triElem<1, 2, 1, 2>(X1, X2, i, j)
           + triElem<2, 3, 1, 2>(X2, X3, i, j);
    };
    reduceKey<1, true>(yel, X1, o3, o4);
  }
  KEY_FENCE();
  {  // key 1_-1 : (1,1) (2,2) (3,3)
    auto yel = [&](int i, int j) {
      return triElem<1, 1, 1, 1>(X1, X1, i, j)
           + triElem<2, 2, 1, 1>(X2, X2, i, j)
           + triElem<3, 3, 1, 1>(X3, X3, i, j);
    };
    reduceKey<1, false>(yel, X1, o3, o4);
  }
  KEY_FENCE();
  {  // key 2_1 : (0,2)x2 (1,1) (1,3)x2 (2,2) (3,3)
    auto yel = [&](int i, int j) {
      return triElem<0, 2, 2, 2>(X0, X2, i, j)
           + triElem<1, 1, 2, 1>(X1, X1, i, j)
           + triElem<1, 3, 2, 2>(X1, X3, i, j)
           + triElem<2, 2, 2, 1>(X2, X2, i, j)
           + triElem<3, 3, 2, 1>(X3, X3, i, j);
    };
    reduceKey<2, true>(yel, X2, o3, o4);
  }
  KEY_FENCE();
  {  // key 2_-1 : (1,2)x2 (2,3)x2
    auto yel = [&](int i, int j) {
      return triElem<1, 2, 2, 2>(X1, X2, i, j)
           + triElem<2, 3, 2, 2>(X2, X3, i, j);
    };
    reduceKey<2, false>(yel, X2, o3, o4);
  }
  KEY_FENCE();
  {  // key 3_1 : (0,3)x2 (1,2)x2 (2,3)x2
    auto yel = [&](int i, int j) {
      return triElem<0, 3, 3, 2>(X0, X3, i, j)
           + triElem<1, 2, 3, 2>(X1, X2, i, j)
           + triElem<2, 3, 3, 2>(X2, X3, i, j);
    };
    reduceKey<3, true>(yel, X3, o3, o4);
  }
  KEY_FENCE();
  {  // key 3_-1 : (1,3)x2 (2,2) (3,3)
    auto yel = [&](int i, int j) {
      return triElem<1, 3, 3, 2>(X1, X3, i, j)
           + triElem<2, 2, 3, 1>(X2, X2, i, j)
           + triElem<3, 3, 3, 1>(X3, X3, i, j);
    };
    reduceKey<3, false>(yel, X3, o3, o4);
  }
#undef KEY_FENCE

  reinterpret_cast<float4*>(out)[b] = make_float4(X0[0], o2, o3, o4);
}

extern "C" void kernel_launch(void* const* d_in, const int* in_sizes, int n_in,
                              void* d_out, int out_size, void* d_ws, size_t ws_size,
                              hipStream_t stream) {
  const float* x0 = (const float*)d_in[0];
  const float* x1 = (const float*)d_in[1];
  const float* x2 = (const float*)d_in[2];
  const float* x3 = (const float*)d_in[3];
  float* out = (float*)d_out;
  const int n = in_sizes[0];  // B (x0 has 1 element per b)
  const int block = 256;
  const int grid = (n + block - 1) / block;
  wigner_kernel<<<grid, block, 0, stream>>>(x0, x1, x2, x3, out, n);
}